// Round 19
// baseline (194.281 us; speedup 1.0000x reference)
//
#include <hip/hip_runtime.h>
#include <hip/hip_bf16.h>

// LVQ: out[n] = classes[argmin_k ||x_n - c_k||^2]
// N=65536, D=512, K=1024, classes int32.
//
// Round 19: r15 with BK 32->64 (8 K-tiles, 64 MFMA/wave per barrier).
// Rationale: r9's 3-pass did 3x MFMA in 1.4x time (44% vs 19% util) on the
// same skeleton -> per-tile sync cost dominates; amortize it 2x.
//  A: fp32 X reg-staged 1 tile deep (8 float4; tile now covers HBM lat),
//     cvt RN, 4x ds_write_b128 to 8-group swizzled LDS (sg = g^((row>>1)&7);
//     frag reads stay 2 lanes/bank-quad = free).
//  B: pre-split Ch via global_load_lds (source-side swizzle, linear dest).
//  vmcnt: top 0 (drains B(t), issued a full tile ago), tail 4 (forces
//  X(t+1), keeps B(t+1) in flight). 1 barrier/tile, 8 tiles.
//  Epilogue stores score = csq - 2*cross (fp16); phase2 unchanged.
//  Fallback (ws too small): round-9 3-pass bf16-split path (verified).

#define N_ROWS 65536
#define DIM    512
#define K_CB   1024
#define NT2    8           // DIM / BK, BK=64
#define LDSB2  32768       // elems per buffer: A[0,16384) B[16384,32768)
#define LDSBUF 32768       // fallback r9 buffer elems
#define NT     16

typedef short bf16x8 __attribute__((ext_vector_type(8)));
typedef float f32x4  __attribute__((ext_vector_type(4)));
typedef unsigned short u16x8 __attribute__((ext_vector_type(8)));

__device__ __forceinline__ unsigned short f2bf_rn(float f) {
    unsigned u = __float_as_uint(f);
    unsigned r = (u + 0x7FFFu + ((u >> 16) & 1u)) >> 16;
    return (unsigned short)r;
}
__device__ __forceinline__ float bf2f(unsigned short h) {
    return __uint_as_float(((unsigned)h) << 16);
}
__device__ __forceinline__ bf16x8 pack_bf8(float4 a, float4 b) {
    bf16x8 r;
    r[0] = (short)f2bf_rn(a.x); r[1] = (short)f2bf_rn(a.y);
    r[2] = (short)f2bf_rn(a.z); r[3] = (short)f2bf_rn(a.w);
    r[4] = (short)f2bf_rn(b.x); r[5] = (short)f2bf_rn(b.y);
    r[6] = (short)f2bf_rn(b.z); r[7] = (short)f2bf_rn(b.w);
    return r;
}

__device__ __forceinline__ void gload16(const void* g, void* l) {
    __builtin_amdgcn_global_load_lds(
        (const __attribute__((address_space(1))) unsigned int*)g,
        (__attribute__((address_space(3))) unsigned int*)l, 16, 0, 0);
}

// ---------------- csq[k] = sum_d C[k][d]^2 (fp32) ----------------
__global__ void csq_kernel(const float* __restrict__ C, float* __restrict__ csq) {
    int wid  = (blockIdx.x * blockDim.x + threadIdx.x) >> 6;   // one wave per k
    int lane = threadIdx.x & 63;
    const float4* p = (const float4*)(C + (size_t)wid * DIM);
    float4 a = p[lane * 2];
    float4 b = p[lane * 2 + 1];
    float s = a.x*a.x + a.y*a.y + a.z*a.z + a.w*a.w
            + b.x*b.x + b.y*b.y + b.z*b.z + b.w*b.w;
    #pragma unroll
    for (int m = 1; m < 64; m <<= 1) s += __shfl_xor(s, m, 64);
    if (lane == 0) csq[wid] = s;
}

// ---------------- fp32 -> bf16 (hi only, RN), 16B stores ----------------
__global__ void split_hi8(const float* __restrict__ src,
                          unsigned short* __restrict__ h, int n8) {
    int stride = gridDim.x * 256;
    for (int i = blockIdx.x * 256 + threadIdx.x; i < n8; i += stride) {
        const float4* p = (const float4*)(src + (size_t)i * 8);
        float4 a = p[0], b = p[1];
        u16x8 o;
        o[0] = f2bf_rn(a.x); o[1] = f2bf_rn(a.y);
        o[2] = f2bf_rn(a.z); o[3] = f2bf_rn(a.w);
        o[4] = f2bf_rn(b.x); o[5] = f2bf_rn(b.y);
        o[6] = f2bf_rn(b.z); o[7] = f2bf_rn(b.w);
        *(u16x8*)(h + (size_t)i * 8) = o;
    }
}

// ---------------- Phase 1: fused-cvt BK=64 GEMM -> fp16 scores -------------
// LDS per buffer: A[0,16384) B[16384,32768); [row][group 0..7][8 elems];
// slot s of row r holds GLOBAL k-group s^((r>>1)&7).
__global__ __launch_bounds__(512, 1)
void gemm_scores(const float* __restrict__ X,
                 const unsigned short* __restrict__ Ch,
                 const float* __restrict__ csq,
                 _Float16* __restrict__ scores) {
    extern __shared__ unsigned short smem[];   // 2 * LDSB2 elems (128 KB)

    // XCD-aware mapping: 4 col-tiles of one row-tile on one XCD.
    int b  = blockIdx.x;
    int x  = b & 7;
    int m8 = b >> 3;                   // 0..127
    int rowtile = x * 32 + (m8 >> 2);  // 0..255
    int coltile = m8 & 3;              // 0..3
    int n0 = rowtile * 256;
    int k0 = coltile * 256;

    int tid  = threadIdx.x;
    int w    = tid >> 6;
    int lane = tid & 63;
    int wr   = w >> 2, wc = w & 3;     // 2M x 4N waves; wave tile 128x64
    int rbase = wr * 128, cbase = wc * 64;
    int lrow = lane & 15;
    int lk   = lane >> 4;
    int swz  = (lrow >> 1) & 7;
    int sgk0 = (lk)     ^ swz;         // k-step 0 slot
    int sgk1 = (4 + lk) ^ swz;         // k-step 1 slot

    // A staging: thread -> row ra = tid>>1 (0..255), half h = tid&1
    // (fp32 cols h*32..h*32+31 of the 64-wide k-tile; lanes pairwise
    // contiguous -> coalesced).
    int ra = tid >> 1;
    int h  = tid & 1;
    int aswz = (ra >> 1) & 7;
    const float* xsrc = X + (size_t)(n0 + ra) * DIM + h * 32;
    int ad0 = ra * 64 + ((h * 4 + 0) ^ aswz) * 8;
    int ad1 = ra * 64 + ((h * 4 + 1) ^ aswz) * 8;
    int ad2 = ra * 64 + ((h * 4 + 2) ^ aswz) * 8;
    int ad3 = ra * 64 + ((h * 4 + 3) ^ aswz) * 8;

    // B staging via gload_lds: thread -> rb = tid>>3 (0..63), grp = tid&7;
    // rows rb, rb+64, rb+128, rb+192. dest = 16384 + rblk*4096 + w*512
    // (+ lane*16B by HW: (l>>3)*64 + (l&7)*8 = l*8 elems -> linear).
    int rb  = tid >> 3;
    int grp = tid & 7;
    int gg  = grp ^ ((rb >> 1) & 7);   // same for all 4 row-blocks
    size_t oB = (size_t)(k0 + rb) * DIM + gg * 8;
    int dB  = 16384 + w * 512;

    f32x4 acc[8][4];
    #pragma unroll
    for (int i = 0; i < 8; i++)
        #pragma unroll
        for (int j = 0; j < 4; j++)
            acc[i][j] = (f32x4){0.f, 0.f, 0.f, 0.f};

    auto issue_B = [&](int tn) {
        unsigned short* bufn = smem + (tn & 1) * LDSB2;
        size_t d = (size_t)tn * 64;
        gload16(Ch + oB + d,                   bufn + dB);
        gload16(Ch + oB + d + (size_t)64*DIM,  bufn + dB + 4096);
        gload16(Ch + oB + d + (size_t)128*DIM, bufn + dB + 8192);
        gload16(Ch + oB + d + (size_t)192*DIM, bufn + dB + 12288);
    };

    float4 xq0, xq1, xq2, xq3, xq4, xq5, xq6, xq7;   // X(t+1) regs (1 set)

    auto loadX = [&](int tn) {
        const float4* q = (const float4*)(xsrc + tn * 64);
        xq0 = q[0]; xq1 = q[1]; xq2 = q[2]; xq3 = q[3];
        xq4 = q[4]; xq5 = q[5]; xq6 = q[6]; xq7 = q[7];
    };
    auto writeA = [&](unsigned short* nb) {
        *(bf16x8*)(nb + ad0) = pack_bf8(xq0, xq1);
        *(bf16x8*)(nb + ad1) = pack_bf8(xq2, xq3);
        *(bf16x8*)(nb + ad2) = pack_bf8(xq4, xq5);
        *(bf16x8*)(nb + ad3) = pack_bf8(xq6, xq7);
    };

    // prologue: X(0) -> regs; issue B(0); write A(0) to buf0.
    loadX(0);
    issue_B(0);
    asm volatile("s_waitcnt vmcnt(4)" ::: "memory");   // X(0) landed
    writeA(smem);

    for (int t = 0; t < NT2; ++t) {
        // B(t) issued a full tile ago (prologue/body t-1) -> cheap drain.
        asm volatile("s_waitcnt vmcnt(0)" ::: "memory");
        asm volatile("s_waitcnt lgkmcnt(0)" ::: "memory"); // our A-writes done
        __builtin_amdgcn_s_barrier();
        asm volatile("" ::: "memory");

        const unsigned short* buf = smem + (t & 1) * LDSB2;
        unsigned short* nbuf = smem + ((t + 1) & 1) * LDSB2;
        const unsigned short* pA = buf + (rbase + lrow) * 64;
        const unsigned short* pB = buf + 16384 + (cbase + lrow) * 64;
        bool pre = (t + 1 < NT2);

        if (pre) {
            loadX(t + 1);       // 8 loads (oldest)
            issue_B(t + 1);     // 4 loads
        }

        bf16x8 ah[8], bh[4];
        // ---- k-step 0 ----
        #pragma unroll
        for (int n = 0; n < 4; n++) bh[n] = *(const bf16x8*)(pB + n * 1024 + sgk0 * 8);
        #pragma unroll
        for (int m = 0; m < 8; m++) ah[m] = *(const bf16x8*)(pA + m * 1024 + sgk0 * 8);
        __builtin_amdgcn_s_setprio(1);
        #pragma unroll
        for (int m = 0; m < 8; m++)
            #pragma unroll
            for (int n = 0; n < 4; n++)
                acc[m][n] = __builtin_amdgcn_mfma_f32_16x16x32_bf16(ah[m], bh[n], acc[m][n], 0, 0, 0);
        __builtin_amdgcn_s_setprio(0);
        // ---- k-step 1 ----
        #pragma unroll
        for (int n = 0; n < 4; n++) bh[n] = *(const bf16x8*)(pB + n * 1024 + sgk1 * 8);
        #pragma unroll
        for (int m = 0; m < 8; m++) ah[m] = *(const bf16x8*)(pA + m * 1024 + sgk1 * 8);
        __builtin_amdgcn_s_setprio(1);
        #pragma unroll
        for (int m = 0; m < 8; m++)
            #pragma unroll
            for (int n = 0; n < 4; n++)
                acc[m][n] = __builtin_amdgcn_mfma_f32_16x16x32_bf16(ah[m], bh[n], acc[m][n], 0, 0, 0);
        __builtin_amdgcn_s_setprio(0);

        // tail: force X(t+1) (oldest 8), keep B(t+1) 4 in flight; write A.
        if (pre) {
            asm volatile("s_waitcnt vmcnt(4)" ::: "memory");
            writeA(nbuf);
        }
    }

    // epilogue: store fp16 SCORES (csq - 2*cross).
    // C/D: col = lane&15, row = (lane>>4)*4 + reg.
    float cs[4];
    #pragma unroll
    for (int n = 0; n < 4; n++) cs[n] = csq[k0 + cbase + n * 16 + lrow];

    #pragma unroll
    for (int m = 0; m < 8; m++) {
        int grow = n0 + rbase + m * 16 + lk * 4;
        #pragma unroll
        for (int r = 0; r < 4; r++) {
            _Float16* sp = scores + (size_t)(grow + r) * K_CB + k0 + cbase + lrow;
            #pragma unroll
            for (int n = 0; n < 4; n++)
                sp[n * 16] = (_Float16)(cs[n] - 2.0f * acc[m][n][r]);
        }
    }
}

// ---------------- Phase 2: shortlist + exact certify (verified) ----------
// stored score_k ~ csq[k] - 2*x.c_k with |err| <= 5.5 =: D. THR=16 > 2*D.
struct H8 { _Float16 v[8]; };

__global__ __launch_bounds__(256)
void phase2_kernel(const float* __restrict__ X, const float* __restrict__ C,
                   const float* __restrict__ csq,
                   const _Float16* __restrict__ scores,
                   const int* __restrict__ classes, int* __restrict__ out) {
    int lane = threadIdx.x & 63;
    int n = blockIdx.x * 4 + (threadIdx.x >> 6);   // one wave per row

    float s[16];
    {
        const _Float16* sp16 = scores + (size_t)n * K_CB + lane * 16;
        H8 h0 = *(const H8*)sp16;
        H8 h1 = *(const H8*)(sp16 + 8);
        #pragma unroll
        for (int j = 0; j < 8; j++) {
            s[j]     = (float)h0.v[j];
            s[8 + j] = (float)h1.v[j];
        }
    }

    float mn = s[0];
    #pragma unroll
    for (int j = 1; j < 16; j++) mn = fminf(mn, s[j]);
    #pragma unroll
    for (int m = 1; m < 64; m <<= 1) mn = fminf(mn, __shfl_xor(mn, m, 64));

    float thr = mn + 16.0f;
    unsigned fl = 0;
    #pragma unroll
    for (int j = 0; j < 16; j++) fl |= (unsigned)(s[j] <= thr) << j;
    int cnt = __popc(fl);
    #pragma unroll
    for (int m = 1; m < 64; m <<= 1) cnt += __shfl_xor(cnt, m, 64);

    int bestk;
    if (cnt == 1) {
        int kk = 0x7fffffff;
        #pragma unroll
        for (int j = 0; j < 16; j++)
            if ((fl >> j) & 1) kk = lane * 16 + j;
        #pragma unroll
        for (int m = 1; m < 64; m <<= 1) kk = min(kk, __shfl_xor(kk, m, 64));
        bestk = kk;
    } else {
        const float4* xp = (const float4*)(X + (size_t)n * DIM + lane * 8);
        float4 x0 = xp[0], x1 = xp[1];
        float bv = 3.4e38f;
        int bk = 0x7fffffff;
        #pragma unroll 1
        for (int j = 0; j < 16; j++) {
            unsigned long long mask = __ballot((fl >> j) & 1);
            while (mask) {
                int l = __ffsll((unsigned long long)mask) - 1;
                mask &= mask - 1;
                int k = l * 16 + j;                       // wave-uniform
                const float4* cp = (const float4*)(C + (size_t)k * DIM + lane * 8);
                float4 y0 = cp[0], y1 = cp[1];
                float d = x0.x*y0.x + x0.y*y0.y + x0.z*y0.z + x0.w*y0.w
                        + x1.x*y1.x + x1.y*y1.y + x1.z*y1.z + x1.w*y1.w;
                #pragma unroll
                for (int m = 1; m < 64; m <<= 1) d += __shfl_xor(d, m, 64);
                float se = csq[k] - 2.0f * d;             // exact fp32 score
                if (se < bv || (se == bv && k < bk)) { bv = se; bk = k; }
            }
        }
        bestk = bk;
    }
    if (lane == 0) out[n] = classes[bestk];
}

// ======================= fallback path (round-9, verified) =================
__global__ void init_kernel(unsigned long long* __restrict__ packed) {
    int n = blockIdx.x * 256 + threadIdx.x;
    if (n < N_ROWS) packed[n] = ~0ull;
}

__global__ void split_kernel(const float* __restrict__ src,
                             unsigned short* __restrict__ h,
                             unsigned short* __restrict__ l, int n4) {
    int stride = gridDim.x * 256;
    for (int i = blockIdx.x * 256 + threadIdx.x; i < n4; i += stride) {
        float4 v = ((const float4*)src)[i];
        ushort4 hh, ll;
        float f;
        f = v.x; hh.x = f2bf_rn(f); ll.x = f2bf_rn(f - bf2f(hh.x));
        f = v.y; hh.y = f2bf_rn(f); ll.y = f2bf_rn(f - bf2f(hh.y));
        f = v.z; hh.z = f2bf_rn(f); ll.z = f2bf_rn(f - bf2f(hh.z));
        f = v.w; hh.w = f2bf_rn(f); ll.w = f2bf_rn(f - bf2f(hh.w));
        ((ushort4*)h)[i] = hh;
        ((ushort4*)l)[i] = ll;
    }
}

__global__ __launch_bounds__(512, 2)
void gemm_argmin(const unsigned short* __restrict__ Xh,
                 const unsigned short* __restrict__ Xl,
                 const unsigned short* __restrict__ Ch,
                 const unsigned short* __restrict__ Cl,
                 const float* __restrict__ csq,
                 unsigned long long* __restrict__ packed) {
    extern __shared__ unsigned short smem[];

    int b  = blockIdx.x;
    int x  = b & 7;
    int m8 = b >> 3;
    int rowtile = x * 32 + (m8 >> 2);
    int coltile = m8 & 3;
    int n0 = rowtile * 256;
    int k0 = coltile * 256;

    int tid  = threadIdx.x;
    int w    = tid >> 6;
    int lane = tid & 63;
    int wr   = w >> 2, wc = w & 3;
    int rbase = wr * 128, cbase = wc * 64;
    int lrow = lane & 15;
    int lk   = lane >> 4;
    int sg   = lk ^ ((lrow >> 1) & 3);

    int srow = tid >> 2;
    int sgrp = tid & 3;
    int r1   = (srow < 64) ? srow : srow + 64;
    int ggA  = sgrp ^ ((r1 >> 1) & 3);
    int gB   = sgrp ^ ((srow >> 1) & 3);
    size_t oA1 = (size_t)(n0 + r1) * DIM + ggA * 8;
    size_t oA2 = oA1 + (size_t)64 * DIM;
    size_t oB0 = (size_t)(k0 + srow) * DIM + gB * 8;
    size_t oB1 = oB0 + (size_t)128 * DIM;
    int rowA1_0 = (w < 4) ? w * 16 : w * 16 + 64;
    int dA1  = rowA1_0 * 32;
    int dA2  = dA1 + 2048;
    int dB0  = 16384 + w * 512;
    int dB1  = dB0 + 4096;
    int dBl0 = dB0 + 8192;
    int dBl1 = dB1 + 8192;

    f32x4 acc[8][4];
    #pragma unroll
    for (int i = 0; i < 8; i++)
        #pragma unroll
        for (int j = 0; j < 4; j++)
            acc[i][j] = (f32x4){0.f, 0.f, 0.f, 0.f};

    bf16x8 bh[4], bl[4];

    auto issue_tile = [&](int t) {
        unsigned short* bufn = smem + (t & 1) * LDSBUF;
        size_t d = (size_t)t * 32;
        gload16(Xh + oA1 + d, bufn + dA1);
        gload16(Xl + oA1 + d, bufn + 8192 + dA1);
        gload16(Ch + oB0 + d, bufn + dB0);
        gload16(Ch + oB1 + d, bufn + dB1);
        gload16(Cl + oB0 + d, bufn + dBl0);
        gload16(Cl + oB1 + d, bufn + dBl1);
        gload16(Xh + oA2 + d, bufn + dA2);
        gload16(Xl + oA2 + d, bufn + 8192 + dA2);
    };

    auto mfma_half = [&](int mb, const bf16x8* ah, const bf16x8* al) {
        __builtin_amdgcn_s_setprio(1);
        #pragma unroll
        for (int mm = 0; mm < 4; mm++)
            #pragma unroll
            for (int n = 0; n < 4; n++)
                acc[mb + mm][n] = __builtin_amdgcn_mfma_f32_16x16x32_bf16(ah[mm], bh[n], acc[mb + mm][n], 0, 0, 0);
        #pragma unroll
        for (int mm = 0; mm < 4; mm++)
            #pragma unroll
            for (int n = 0; n < 4; n++)
                acc[mb + mm][n] = __builtin_amdgcn_mfma_f32_16x16x32_bf16(ah[mm], bl[n], acc[mb + mm][n], 0, 0, 0);
        #pragma unroll
        for (int mm = 0; mm < 4; mm++)
            #pragma unroll
            for (int n = 0; n < 4; n++)
                acc[mb + mm][n] = __builtin_amdgcn_mfma_f32_16x16x32_bf16(al[mm], bh[n], acc[mb + mm][n], 0, 0, 0);
        __builtin_amdgcn_s_setprio(0);
    };

    issue_tile(0);

    for (int t = 0; t < NT; ++t) {
        asm volatile("s_waitcnt vmcnt(0)" ::: "memory");
        __builtin_amdgcn_s_barrier();
        asm volatile("" ::: "memory");

        const unsigned short* buf = smem + (t & 1) * LDSBUF;
        const unsigned short* pA = buf + (rbase + lrow) * 32 + sg * 8;
        const unsigned short* pB = buf + 16384 + (cbase + lrow) * 32 + sg * 8;

        #pragma unroll
        for (int n = 0; n < 4; n++) {
            bh[n] = *(const bf16x8*)(pB + n * 512);
            bl[n] = *(const bf16x8*)(pB + 8192 + n * 512);
        }
        bf16x8 ah[4], al[4];
        #pragma unroll
        for (int mm = 0; mm < 4; mm++) {
            ah[mm] = *(const bf16x8*)(pA + mm * 512);
            al[mm] = *(const bf16x8*)(pA + 8192 + mm * 512);
        }
        if (t + 1 < NT) issue_tile(t + 1);

        mfma_half(0, ah, al);

        bf16x8 ah2[4], al2[4];
        #pragma unroll
        for (int mm = 0; mm < 4; mm++) {
            ah2[mm] = *(const bf16x8*)(pA + (4 + mm) * 512);
            al2[mm] = *(const bf16x8*)(pA + 8192 + (4 + mm) * 512);
        }
        mfma_half(4, ah2, al2);
    }

    float cs[4];
    #pragma unroll
    for (int n = 0; n < 4; n++) cs[n] = csq[k0 + cbase + n * 16 + lrow];

    #pragma unroll
    for (int m = 0; m < 8; m++) {
        #pragma unroll
        for (int r = 0; r < 4; r++) {
            unsigned long long best = ~0ull;
            #pragma unroll
            for (int n = 0; n < 4; n++) {
                float s = cs[n] - 2.0f * acc[m][n][r];
                unsigned kb  = __float_as_uint(s);
                unsigned key = kb ^ (unsigned)(((int)kb >> 31) | 0x80000000);
                unsigned col = (unsigned)(k0 + cbase + n * 16 + lrow);
                unsigned long long pk = (((unsigned long long)key) << 32) | col;
                best = pk < best ? pk : best;
            }
            #pragma unroll
            for (int mask = 1; mask <= 8; mask <<= 1) {
                unsigned hi = __shfl_xor((unsigned)(best >> 32), mask, 64);
                unsigned lo = __shfl_xor((unsigned)(best & 0xFFFFFFFFu), mask, 64);
                unsigned long long other = (((unsigned long long)hi) << 32) | lo;
                best = other < best ? other : best;
            }
            if (lrow == 0) {
                int grow = n0 + rbase + m * 16 + lk * 4 + r;
                atomicMin(&packed[grow], best);
            }
        }
    }
}

__global__ void map_kernel(const unsigned long long* __restrict__ packed,
                           const int* __restrict__ classes,
                           int* __restrict__ out) {
    int n = blockIdx.x * 256 + threadIdx.x;
    if (n < N_ROWS) {
        unsigned col = (unsigned)(packed[n] & 0xFFFFFFFFull);
        out[n] = classes[col];
    }
}

extern "C" void kernel_launch(void* const* d_in, const int* in_sizes, int n_in,
                              void* d_out, int out_size, void* d_ws, size_t ws_size,
                              hipStream_t stream) {
    const float* X       = (const float*)d_in[0];
    const float* C       = (const float*)d_in[1];
    const int*   classes = (const int*)d_in[2];
    int*         out     = (int*)d_out;
    char* ws = (char*)d_ws;

    // ---- fast path layout: csq | Ch | scores(fp16) ----
    {
        size_t off = 0;
        float* csq = (float*)(ws + off);                  off += 4096;
        unsigned short* Ch = (unsigned short*)(ws + off); off += (size_t)K_CB * DIM * 2;
        _Float16* scores = (_Float16*)(ws + off);         off += (size_t)N_ROWS * K_CB * 2;
        if (ws_size >= off) {
            csq_kernel<<<K_CB / 4, 256, 0, stream>>>(C, csq);
            split_hi8<<<256, 256, 0, stream>>>(C, Ch, K_CB * DIM / 8);
            hipFuncSetAttribute((const void*)gemm_scores,
                                hipFuncAttributeMaxDynamicSharedMemorySize,
                                2 * LDSB2 * (int)sizeof(unsigned short));
            gemm_scores<<<(N_ROWS / 256) * (K_CB / 256), 512,
                          2 * LDSB2 * sizeof(unsigned short), stream>>>(
                X, Ch, csq, scores);
            phase2_kernel<<<N_ROWS / 4, 256, 0, stream>>>(X, C, csq, scores, classes, out);
            return;
        }
    }

    // ---- fallback: round-9 3-pass path ----
    size_t off = 0;
    unsigned long long* packed = (unsigned long long*)(ws + off); off += (size_t)N_ROWS * 8;
    float* csq = (float*)(ws + off);                              off += (size_t)K_CB * 4;
    unsigned short* Xh = (unsigned short*)(ws + off);             off += (size_t)N_ROWS * DIM * 2;
    unsigned short* Xl = (unsigned short*)(ws + off);             off += (size_t)N_ROWS * DIM * 2;
    unsigned short* Ch = (unsigned short*)(ws + off);             off += (size_t)K_CB * DIM * 2;
    unsigned short* Cl = (unsigned short*)(ws + off);             off += (size_t)K_CB * DIM * 2;

    init_kernel<<<N_ROWS / 256, 256, 0, stream>>>(packed);
    csq_kernel<<<K_CB / 4, 256, 0, stream>>>(C, csq);
    split_kernel<<<2048, 256, 0, stream>>>(X, Xh, Xl, N_ROWS * DIM / 4);
    split_kernel<<<512, 256, 0, stream>>>(C, Ch, Cl, K_CB * DIM / 4);
    hipFuncSetAttribute((const void*)gemm_argmin,
                        hipFuncAttributeMaxDynamicSharedMemorySize,
                        2 * LDSBUF * (int)sizeof(unsigned short));
    gemm_argmin<<<(N_ROWS / 256) * (K_CB / 256), 512,
                  2 * LDSBUF * sizeof(unsigned short), stream>>>(
        Xh, Xl, Ch, Cl, csq, packed);
    map_kernel<<<N_ROWS / 256, 256, 0, stream>>>(packed, classes, out);
}

// Round 20
// 193.329 us; speedup vs baseline: 1.0049x; 1.0049x over previous
//
#include <hip/hip_runtime.h>
#include <hip/hip_bf16.h>

// LVQ: out[n] = classes[argmin_k ||x_n - c_k||^2]
// N=65536, D=512, K=1024, classes int32.
//
// Round 20: BK=64 with DUAL-32-HALF LDS layout (fixes r19's 2.1M bank
// conflicts: 128B row stride removed row bits from the bank index; two
// 64B-stride halves restore the r15-verified 0-conflict pattern).
//  LDS/buffer: A0[0,8192) A1[8192,16384) B0[16384,24576) B1[24576,32768),
//  each [row][slot 0..3][8], slot s holds global k-group s^((row>>1)&3).
//  A: fp32 X reg-staged 1 tile deep (8 float4 = 1 row x 32 cols x half p),
//     cvt RN, 4x ds_write_b128. B: pre-split Ch via global_load_lds
//     (source-side swizzle, linear dest), 4 gloads/thread/tile.
//  Sync: 1 barrier/tile (8 tiles); top vmcnt(0) drains B(t) (issued a full
//  tile ago); tail vmcnt(4) forces X(t+1), keeps B(t+1) in flight.
//  Epilogue stores score = csq - 2*cross (fp16); phase2 unchanged.
//  Fallback (ws too small): round-9 3-pass bf16-split path (verified).

#define N_ROWS 65536
#define DIM    512
#define K_CB   1024
#define NT2    8           // DIM / BK, BK=64
#define LDSB2  32768       // elems per buffer (64 KB): A0|A1|B0|B1
#define LDSBUF 32768       // fallback r9 buffer elems
#define NT     16

typedef short bf16x8 __attribute__((ext_vector_type(8)));
typedef float f32x4  __attribute__((ext_vector_type(4)));
typedef unsigned short u16x8 __attribute__((ext_vector_type(8)));

__device__ __forceinline__ unsigned short f2bf_rn(float f) {
    unsigned u = __float_as_uint(f);
    unsigned r = (u + 0x7FFFu + ((u >> 16) & 1u)) >> 16;
    return (unsigned short)r;
}
__device__ __forceinline__ float bf2f(unsigned short h) {
    return __uint_as_float(((unsigned)h) << 16);
}
__device__ __forceinline__ bf16x8 pack_bf8(float4 a, float4 b) {
    bf16x8 r;
    r[0] = (short)f2bf_rn(a.x); r[1] = (short)f2bf_rn(a.y);
    r[2] = (short)f2bf_rn(a.z); r[3] = (short)f2bf_rn(a.w);
    r[4] = (short)f2bf_rn(b.x); r[5] = (short)f2bf_rn(b.y);
    r[6] = (short)f2bf_rn(b.z); r[7] = (short)f2bf_rn(b.w);
    return r;
}

__device__ __forceinline__ void gload16(const void* g, void* l) {
    __builtin_amdgcn_global_load_lds(
        (const __attribute__((address_space(1))) unsigned int*)g,
        (__attribute__((address_space(3))) unsigned int*)l, 16, 0, 0);
}

// ---------------- csq[k] = sum_d C[k][d]^2 (fp32) ----------------
__global__ void csq_kernel(const float* __restrict__ C, float* __restrict__ csq) {
    int wid  = (blockIdx.x * blockDim.x + threadIdx.x) >> 6;   // one wave per k
    int lane = threadIdx.x & 63;
    const float4* p = (const float4*)(C + (size_t)wid * DIM);
    float4 a = p[lane * 2];
    float4 b = p[lane * 2 + 1];
    float s = a.x*a.x + a.y*a.y + a.z*a.z + a.w*a.w
            + b.x*b.x + b.y*b.y + b.z*b.z + b.w*b.w;
    #pragma unroll
    for (int m = 1; m < 64; m <<= 1) s += __shfl_xor(s, m, 64);
    if (lane == 0) csq[wid] = s;
}

// ---------------- fp32 -> bf16 (hi only, RN), 16B stores ----------------
__global__ void split_hi8(const float* __restrict__ src,
                          unsigned short* __restrict__ h, int n8) {
    int stride = gridDim.x * 256;
    for (int i = blockIdx.x * 256 + threadIdx.x; i < n8; i += stride) {
        const float4* p = (const float4*)(src + (size_t)i * 8);
        float4 a = p[0], b = p[1];
        u16x8 o;
        o[0] = f2bf_rn(a.x); o[1] = f2bf_rn(a.y);
        o[2] = f2bf_rn(a.z); o[3] = f2bf_rn(a.w);
        o[4] = f2bf_rn(b.x); o[5] = f2bf_rn(b.y);
        o[6] = f2bf_rn(b.z); o[7] = f2bf_rn(b.w);
        *(u16x8*)(h + (size_t)i * 8) = o;
    }
}

// ---------------- Phase 1: fused-cvt BK=64 GEMM -> fp16 scores -------------
__global__ __launch_bounds__(512, 1)
void gemm_scores(const float* __restrict__ X,
                 const unsigned short* __restrict__ Ch,
                 const float* __restrict__ csq,
                 _Float16* __restrict__ scores) {
    extern __shared__ unsigned short smem[];   // 2 * LDSB2 elems (128 KB)

    // XCD-aware mapping: 4 col-tiles of one row-tile on one XCD.
    int b  = blockIdx.x;
    int x  = b & 7;
    int m8 = b >> 3;                   // 0..127
    int rowtile = x * 32 + (m8 >> 2);  // 0..255
    int coltile = m8 & 3;              // 0..3
    int n0 = rowtile * 256;
    int k0 = coltile * 256;

    int tid  = threadIdx.x;
    int w    = tid >> 6;
    int lane = tid & 63;
    int wr   = w >> 2, wc = w & 3;     // 2M x 4N waves; wave tile 128x64
    int rbase = wr * 128, cbase = wc * 64;
    int lrow = lane & 15;
    int lk   = lane >> 4;
    int sg   = lk ^ ((lrow >> 1) & 3); // r15-verified slot (per half)

    // A staging: thread -> row ra = tid>>1 (0..255), half p = tid&1
    // (fp32 cols p*32..p*32+31 of the 64-wide tile).
    int ra = tid >> 1;
    int p_ = tid & 1;
    int aswz = (ra >> 1) & 3;
    const float* xsrc = X + (size_t)(n0 + ra) * DIM + p_ * 32;
    int abase = p_ * 8192 + ra * 32;
    int ad0 = abase + ((0 ^ aswz) * 8);
    int ad1 = abase + ((1 ^ aswz) * 8);
    int ad2 = abase + ((2 ^ aswz) * 8);
    int ad3 = abase + ((3 ^ aswz) * 8);

    // B staging via gload_lds: thread -> srow = tid>>2 (0..127), sgrp=tid&3;
    // rows srow and srow+128, halves 0/1. Linear dest per (half, rowblock).
    int srow = tid >> 2;
    int sgrp = tid & 3;
    int gB   = sgrp ^ ((srow >> 1) & 3);
    size_t oB = (size_t)(k0 + srow) * DIM + gB * 8;   // + t*64 + p*32
    int dB   = 16384 + w * 512;                       // + p*8192, +4096 rows

    f32x4 acc[8][4];
    #pragma unroll
    for (int i = 0; i < 8; i++)
        #pragma unroll
        for (int j = 0; j < 4; j++)
            acc[i][j] = (f32x4){0.f, 0.f, 0.f, 0.f};

    auto issue_B = [&](int tn) {
        unsigned short* bufn = smem + (tn & 1) * LDSB2;
        size_t d = (size_t)tn * 64;
        gload16(Ch + oB + d,                        bufn + dB);            // p0, rb0
        gload16(Ch + oB + d + (size_t)128*DIM,      bufn + dB + 4096);     // p0, rb1
        gload16(Ch + oB + d + 32,                   bufn + dB + 8192);     // p1, rb0
        gload16(Ch + oB + d + 32 + (size_t)128*DIM, bufn + dB + 12288);    // p1, rb1
    };

    float4 xq0, xq1, xq2, xq3, xq4, xq5, xq6, xq7;   // X(t+1) regs

    auto loadX = [&](int tn) {
        const float4* q = (const float4*)(xsrc + tn * 64);
        xq0 = q[0]; xq1 = q[1]; xq2 = q[2]; xq3 = q[3];
        xq4 = q[4]; xq5 = q[5]; xq6 = q[6]; xq7 = q[7];
    };
    auto writeA = [&](unsigned short* nb) {
        *(bf16x8*)(nb + ad0) = pack_bf8(xq0, xq1);
        *(bf16x8*)(nb + ad1) = pack_bf8(xq2, xq3);
        *(bf16x8*)(nb + ad2) = pack_bf8(xq4, xq5);
        *(bf16x8*)(nb + ad3) = pack_bf8(xq6, xq7);
    };

    // prologue: X(0) -> regs; issue B(0); write A(0) to buf0.
    loadX(0);
    issue_B(0);
    asm volatile("s_waitcnt vmcnt(4)" ::: "memory");   // X(0) landed
    writeA(smem);

    for (int t = 0; t < NT2; ++t) {
        // B(t) issued a full tile ago -> cheap drain.
        asm volatile("s_waitcnt vmcnt(0)" ::: "memory");
        asm volatile("s_waitcnt lgkmcnt(0)" ::: "memory"); // our A-writes done
        __builtin_amdgcn_s_barrier();
        asm volatile("" ::: "memory");

        const unsigned short* buf = smem + (t & 1) * LDSB2;
        unsigned short* nbuf = smem + ((t + 1) & 1) * LDSB2;
        bool pre = (t + 1 < NT2);

        if (pre) {
            loadX(t + 1);       // 8 loads (oldest)
            issue_B(t + 1);     // 4 loads
        }

        bf16x8 ah[8], bh[4];
        // ---- half 0 (k-step 0) ----
        {
            const unsigned short* pA = buf + (rbase + lrow) * 32 + sg * 8;
            const unsigned short* pB = buf + 16384 + (cbase + lrow) * 32 + sg * 8;
            #pragma unroll
            for (int n = 0; n < 4; n++) bh[n] = *(const bf16x8*)(pB + n * 512);
            #pragma unroll
            for (int m = 0; m < 8; m++) ah[m] = *(const bf16x8*)(pA + m * 512);
            __builtin_amdgcn_s_setprio(1);
            #pragma unroll
            for (int m = 0; m < 8; m++)
                #pragma unroll
                for (int n = 0; n < 4; n++)
                    acc[m][n] = __builtin_amdgcn_mfma_f32_16x16x32_bf16(ah[m], bh[n], acc[m][n], 0, 0, 0);
            __builtin_amdgcn_s_setprio(0);
        }
        // ---- half 1 (k-step 1) ----
        {
            const unsigned short* pA = buf + 8192 + (rbase + lrow) * 32 + sg * 8;
            const unsigned short* pB = buf + 24576 + (cbase + lrow) * 32 + sg * 8;
            #pragma unroll
            for (int n = 0; n < 4; n++) bh[n] = *(const bf16x8*)(pB + n * 512);
            #pragma unroll
            for (int m = 0; m < 8; m++) ah[m] = *(const bf16x8*)(pA + m * 512);
            __builtin_amdgcn_s_setprio(1);
            #pragma unroll
            for (int m = 0; m < 8; m++)
                #pragma unroll
                for (int n = 0; n < 4; n++)
                    acc[m][n] = __builtin_amdgcn_mfma_f32_16x16x32_bf16(ah[m], bh[n], acc[m][n], 0, 0, 0);
            __builtin_amdgcn_s_setprio(0);
        }

        // tail: force X(t+1) (oldest 8), keep B(t+1) in flight; write A.
        if (pre) {
            asm volatile("s_waitcnt vmcnt(4)" ::: "memory");
            writeA(nbuf);
        }
    }

    // epilogue: store fp16 SCORES (csq - 2*cross).
    // C/D: col = lane&15, row = (lane>>4)*4 + reg.
    float cs[4];
    #pragma unroll
    for (int n = 0; n < 4; n++) cs[n] = csq[k0 + cbase + n * 16 + lrow];

    #pragma unroll
    for (int m = 0; m < 8; m++) {
        int grow = n0 + rbase + m * 16 + lk * 4;
        #pragma unroll
        for (int r = 0; r < 4; r++) {
            _Float16* sp = scores + (size_t)(grow + r) * K_CB + k0 + cbase + lrow;
            #pragma unroll
            for (int n = 0; n < 4; n++)
                sp[n * 16] = (_Float16)(cs[n] - 2.0f * acc[m][n][r]);
        }
    }
}

// ---------------- Phase 2: shortlist + exact certify (verified) ----------
// stored score_k ~ csq[k] - 2*x.c_k with |err| <= 5.5 =: D. THR=16 > 2*D.
struct H8 { _Float16 v[8]; };

__global__ __launch_bounds__(256)
void phase2_kernel(const float* __restrict__ X, const float* __restrict__ C,
                   const float* __restrict__ csq,
                   const _Float16* __restrict__ scores,
                   const int* __restrict__ classes, int* __restrict__ out) {
    int lane = threadIdx.x & 63;
    int n = blockIdx.x * 4 + (threadIdx.x >> 6);   // one wave per row

    float s[16];
    {
        const _Float16* sp16 = scores + (size_t)n * K_CB + lane * 16;
        H8 h0 = *(const H8*)sp16;
        H8 h1 = *(const H8*)(sp16 + 8);
        #pragma unroll
        for (int j = 0; j < 8; j++) {
            s[j]     = (float)h0.v[j];
            s[8 + j] = (float)h1.v[j];
        }
    }

    float mn = s[0];
    #pragma unroll
    for (int j = 1; j < 16; j++) mn = fminf(mn, s[j]);
    #pragma unroll
    for (int m = 1; m < 64; m <<= 1) mn = fminf(mn, __shfl_xor(mn, m, 64));

    float thr = mn + 16.0f;
    unsigned fl = 0;
    #pragma unroll
    for (int j = 0; j < 16; j++) fl |= (unsigned)(s[j] <= thr) << j;
    int cnt = __popc(fl);
    #pragma unroll
    for (int m = 1; m < 64; m <<= 1) cnt += __shfl_xor(cnt, m, 64);

    int bestk;
    if (cnt == 1) {
        int kk = 0x7fffffff;
        #pragma unroll
        for (int j = 0; j < 16; j++)
            if ((fl >> j) & 1) kk = lane * 16 + j;
        #pragma unroll
        for (int m = 1; m < 64; m <<= 1) kk = min(kk, __shfl_xor(kk, m, 64));
        bestk = kk;
    } else {
        const float4* xp = (const float4*)(X + (size_t)n * DIM + lane * 8);
        float4 x0 = xp[0], x1 = xp[1];
        float bv = 3.4e38f;
        int bk = 0x7fffffff;
        #pragma unroll 1
        for (int j = 0; j < 16; j++) {
            unsigned long long mask = __ballot((fl >> j) & 1);
            while (mask) {
                int l = __ffsll((unsigned long long)mask) - 1;
                mask &= mask - 1;
                int k = l * 16 + j;                       // wave-uniform
                const float4* cp = (const float4*)(C + (size_t)k * DIM + lane * 8);
                float4 y0 = cp[0], y1 = cp[1];
                float d = x0.x*y0.x + x0.y*y0.y + x0.z*y0.z + x0.w*y0.w
                        + x1.x*y1.x + x1.y*y1.y + x1.z*y1.z + x1.w*y1.w;
                #pragma unroll
                for (int m = 1; m < 64; m <<= 1) d += __shfl_xor(d, m, 64);
                float se = csq[k] - 2.0f * d;             // exact fp32 score
                if (se < bv || (se == bv && k < bk)) { bv = se; bk = k; }
            }
        }
        bestk = bk;
    }
    if (lane == 0) out[n] = classes[bestk];
}

// ======================= fallback path (round-9, verified) =================
__global__ void init_kernel(unsigned long long* __restrict__ packed) {
    int n = blockIdx.x * 256 + threadIdx.x;
    if (n < N_ROWS) packed[n] = ~0ull;
}

__global__ void split_kernel(const float* __restrict__ src,
                             unsigned short* __restrict__ h,
                             unsigned short* __restrict__ l, int n4) {
    int stride = gridDim.x * 256;
    for (int i = blockIdx.x * 256 + threadIdx.x; i < n4; i += stride) {
        float4 v = ((const float4*)src)[i];
        ushort4 hh, ll;
        float f;
        f = v.x; hh.x = f2bf_rn(f); ll.x = f2bf_rn(f - bf2f(hh.x));
        f = v.y; hh.y = f2bf_rn(f); ll.y = f2bf_rn(f - bf2f(hh.y));
        f = v.z; hh.z = f2bf_rn(f); ll.z = f2bf_rn(f - bf2f(hh.z));
        f = v.w; hh.w = f2bf_rn(f); ll.w = f2bf_rn(f - bf2f(hh.w));
        ((ushort4*)h)[i] = hh;
        ((ushort4*)l)[i] = ll;
    }
}

__global__ __launch_bounds__(512, 2)
void gemm_argmin(const unsigned short* __restrict__ Xh,
                 const unsigned short* __restrict__ Xl,
                 const unsigned short* __restrict__ Ch,
                 const unsigned short* __restrict__ Cl,
                 const float* __restrict__ csq,
                 unsigned long long* __restrict__ packed) {
    extern __shared__ unsigned short smem[];

    int b  = blockIdx.x;
    int x  = b & 7;
    int m8 = b >> 3;
    int rowtile = x * 32 + (m8 >> 2);
    int coltile = m8 & 3;
    int n0 = rowtile * 256;
    int k0 = coltile * 256;

    int tid  = threadIdx.x;
    int w    = tid >> 6;
    int lane = tid & 63;
    int wr   = w >> 2, wc = w & 3;
    int rbase = wr * 128, cbase = wc * 64;
    int lrow = lane & 15;
    int lk   = lane >> 4;
    int sg   = lk ^ ((lrow >> 1) & 3);

    int srow = tid >> 2;
    int sgrp = tid & 3;
    int r1   = (srow < 64) ? srow : srow + 64;
    int ggA  = sgrp ^ ((r1 >> 1) & 3);
    int gB   = sgrp ^ ((srow >> 1) & 3);
    size_t oA1 = (size_t)(n0 + r1) * DIM + ggA * 8;
    size_t oA2 = oA1 + (size_t)64 * DIM;
    size_t oB0 = (size_t)(k0 + srow) * DIM + gB * 8;
    size_t oB1 = oB0 + (size_t)128 * DIM;
    int rowA1_0 = (w < 4) ? w * 16 : w * 16 + 64;
    int dA1  = rowA1_0 * 32;
    int dA2  = dA1 + 2048;
    int dB0  = 16384 + w * 512;
    int dB1  = dB0 + 4096;
    int dBl0 = dB0 + 8192;
    int dBl1 = dB1 + 8192;

    f32x4 acc[8][4];
    #pragma unroll
    for (int i = 0; i < 8; i++)
        #pragma unroll
        for (int j = 0; j < 4; j++)
            acc[i][j] = (f32x4){0.f, 0.f, 0.f, 0.f};

    bf16x8 bh[4], bl[4];

    auto issue_tile = [&](int t) {
        unsigned short* bufn = smem + (t & 1) * LDSBUF;
        size_t d = (size_t)t * 32;
        gload16(Xh + oA1 + d, bufn + dA1);
        gload16(Xl + oA1 + d, bufn + 8192 + dA1);
        gload16(Ch + oB0 + d, bufn + dB0);
        gload16(Ch + oB1 + d, bufn + dB1);
        gload16(Cl + oB0 + d, bufn + dBl0);
        gload16(Cl + oB1 + d, bufn + dBl1);
        gload16(Xh + oA2 + d, bufn + dA2);
        gload16(Xl + oA2 + d, bufn + 8192 + dA2);
    };

    auto mfma_half = [&](int mb, const bf16x8* ah, const bf16x8* al) {
        __builtin_amdgcn_s_setprio(1);
        #pragma unroll
        for (int mm = 0; mm < 4; mm++)
            #pragma unroll
            for (int n = 0; n < 4; n++)
                acc[mb + mm][n] = __builtin_amdgcn_mfma_f32_16x16x32_bf16(ah[mm], bh[n], acc[mb + mm][n], 0, 0, 0);
        #pragma unroll
        for (int mm = 0; mm < 4; mm++)
            #pragma unroll
            for (int n = 0; n < 4; n++)
                acc[mb + mm][n] = __builtin_amdgcn_mfma_f32_16x16x32_bf16(ah[mm], bl[n], acc[mb + mm][n], 0, 0, 0);
        #pragma unroll
        for (int mm = 0; mm < 4; mm++)
            #pragma unroll
            for (int n = 0; n < 4; n++)
                acc[mb + mm][n] = __builtin_amdgcn_mfma_f32_16x16x32_bf16(al[mm], bh[n], acc[mb + mm][n], 0, 0, 0);
        __builtin_amdgcn_s_setprio(0);
    };

    issue_tile(0);

    for (int t = 0; t < NT; ++t) {
        asm volatile("s_waitcnt vmcnt(0)" ::: "memory");
        __builtin_amdgcn_s_barrier();
        asm volatile("" ::: "memory");

        const unsigned short* buf = smem + (t & 1) * LDSBUF;
        const unsigned short* pA = buf + (rbase + lrow) * 32 + sg * 8;
        const unsigned short* pB = buf + 16384 + (cbase + lrow) * 32 + sg * 8;

        #pragma unroll
        for (int n = 0; n < 4; n++) {
            bh[n] = *(const bf16x8*)(pB + n * 512);
            bl[n] = *(const bf16x8*)(pB + 8192 + n * 512);
        }
        bf16x8 ah[4], al[4];
        #pragma unroll
        for (int mm = 0; mm < 4; mm++) {
            ah[mm] = *(const bf16x8*)(pA + mm * 512);
            al[mm] = *(const bf16x8*)(pA + 8192 + mm * 512);
        }
        if (t + 1 < NT) issue_tile(t + 1);

        mfma_half(0, ah, al);

        bf16x8 ah2[4], al2[4];
        #pragma unroll
        for (int mm = 0; mm < 4; mm++) {
            ah2[mm] = *(const bf16x8*)(pA + (4 + mm) * 512);
            al2[mm] = *(const bf16x8*)(pA + 8192 + (4 + mm) * 512);
        }
        mfma_half(4, ah2, al2);
    }

    float cs[4];
    #pragma unroll
    for (int n = 0; n < 4; n++) cs[n] = csq[k0 + cbase + n * 16 + lrow];

    #pragma unroll
    for (int m = 0; m < 8; m++) {
        #pragma unroll
        for (int r = 0; r < 4; r++) {
            unsigned long long best = ~0ull;
            #pragma unroll
            for (int n = 0; n < 4; n++) {
                float s = cs[n] - 2.0f * acc[m][n][r];
                unsigned kb  = __float_as_uint(s);
                unsigned key = kb ^ (unsigned)(((int)kb >> 31) | 0x80000000);
                unsigned col = (unsigned)(k0 + cbase + n * 16 + lrow);
                unsigned long long pk = (((unsigned long long)key) << 32) | col;
                best = pk < best ? pk : best;
            }
            #pragma unroll
            for (int mask = 1; mask <= 8; mask <<= 1) {
                unsigned hi = __shfl_xor((unsigned)(best >> 32), mask, 64);
                unsigned lo = __shfl_xor((unsigned)(best & 0xFFFFFFFFu), mask, 64);
                unsigned long long other = (((unsigned long long)hi) << 32) | lo;
                best = other < best ? other : best;
            }
            if (lrow == 0) {
                int grow = n0 + rbase + m * 16 + lk * 4 + r;
                atomicMin(&packed[grow], best);
            }
        }
    }
}

__global__ void map_kernel(const unsigned long long* __restrict__ packed,
                           const int* __restrict__ classes,
                           int* __restrict__ out) {
    int n = blockIdx.x * 256 + threadIdx.x;
    if (n < N_ROWS) {
        unsigned col = (unsigned)(packed[n] & 0xFFFFFFFFull);
        out[n] = classes[col];
    }
}

extern "C" void kernel_launch(void* const* d_in, const int* in_sizes, int n_in,
                              void* d_out, int out_size, void* d_ws, size_t ws_size,
                              hipStream_t stream) {
    const float* X       = (const float*)d_in[0];
    const float* C       = (const float*)d_in[1];
    const int*   classes = (const int*)d_in[2];
    int*         out     = (int*)d_out;
    char* ws = (char*)d_ws;

    // ---- fast path layout: csq | Ch | scores(fp16) ----
    {
        size_t off = 0;
        float* csq = (float*)(ws + off);                  off += 4096;
        unsigned short* Ch = (unsigned short*)(ws + off); off += (size_t)K_CB * DIM * 2;
        _Float16* scores = (_Float16*)(ws + off);         off += (size_t)N_ROWS * K_CB * 2;
        if (ws_size >= off) {
            csq_kernel<<<K_CB / 4, 256, 0, stream>>>(C, csq);
            split_hi8<<<256, 256, 0, stream>>>(C, Ch, K_CB * DIM / 8);
            hipFuncSetAttribute((const void*)gemm_scores,
                                hipFuncAttributeMaxDynamicSharedMemorySize,
                                2 * LDSB2 * (int)sizeof(unsigned short));
            gemm_scores<<<(N_ROWS / 256) * (K_CB / 256), 512,
                          2 * LDSB2 * sizeof(unsigned short), stream>>>(
                X, Ch, csq, scores);
            phase2_kernel<<<N_ROWS / 4, 256, 0, stream>>>(X, C, csq, scores, classes, out);
            return;
        }
    }

    // ---- fallback: round-9 3-pass path ----
    size_t off = 0;
    unsigned long long* packed = (unsigned long long*)(ws + off); off += (size_t)N_ROWS * 8;
    float* csq = (float*)(ws + off);                              off += (size_t)K_CB * 4;
    unsigned short* Xh = (unsigned short*)(ws + off);             off += (size_t)N_ROWS * DIM * 2;
    unsigned short* Xl = (unsigned short*)(ws + off);             off += (size_t)N_ROWS * DIM * 2;
    unsigned short* Ch = (unsigned short*)(ws + off);             off += (size_t)K_CB * DIM * 2;
    unsigned short* Cl = (unsigned short*)(ws + off);             off += (size_t)K_CB * DIM * 2;

    init_kernel<<<N_ROWS / 256, 256, 0, stream>>>(packed);
    csq_kernel<<<K_CB / 4, 256, 0, stream>>>(C, csq);
    split_kernel<<<2048, 256, 0, stream>>>(X, Xh, Xl, N_ROWS * DIM / 4);
    split_kernel<<<512, 256, 0, stream>>>(C, Ch, Cl, K_CB * DIM / 4);
    hipFuncSetAttribute((const void*)gemm_argmin,
                        hipFuncAttributeMaxDynamicSharedMemorySize,
                        2 * LDSBUF * (int)sizeof(unsigned short));
    gemm_argmin<<<(N_ROWS / 256) * (K_CB / 256), 512,
                  2 * LDSBUF * sizeof(unsigned short), stream>>>(
        Xh, Xl, Ch, Cl, csq, packed);
    map_kernel<<<N_ROWS / 256, 256, 0, stream>>>(packed, classes, out);
}

// Round 21
// 155.374 us; speedup vs baseline: 1.2504x; 1.2443x over previous
//
#include <hip/hip_runtime.h>
#include <hip/hip_bf16.h>

// LVQ: out[n] = classes[argmin_k ||x_n - c_k||^2]
// N=65536, D=512, K=1024, classes int32.
//
// FINAL (round 21): revert to the session-best structure (r15/r18,
// 158-161us, absmax 0 both runs).
//  Phase 1 (gemm_scores, ~144us): fused X-conversion GEMM — fp32 X
//    reg-staged 2 tiles deep (coalesced 4-lanes/row), cvt RN, ds_write to
//    swizzled LDS; B = pre-split Ch (1MB) via global_load_lds (source-side
//    swizzle, linear dest). Counted vmcnt (top 4, tail 6 — never 0
//    mid-loop). Epilogue stores score = csq - 2*cross as fp16.
//  Phase 2 (~14us): wave-per-row approx-min over stored scores, shortlist
//    within THR=16 (rigorous: 2*Dmax = 11 < 16), exact fp32 rescore of
//    shortlist; singleton certifies free.
//  Refuted branches: scores-materialized split_X (r13/r14: +24us),
//    fused shortlist epilogue (r16/r17: straggler/codegen drag),
//    BK=64 (r19/r20: write-bank conflicts + 1-block/CU occupancy loss).
//  Fallback (ws too small): round-9 3-pass bf16-split path (verified).

#define N_ROWS 65536
#define DIM    512
#define K_CB   1024
#define NT     16          // DIM / BK, BK=32
#define LDSBUF_F 16384     // fast gemm buffer elems: A[0,8192)|B[8192,16384)
#define LDSBUF   32768     // fallback r9 buffer elems

typedef short bf16x8 __attribute__((ext_vector_type(8)));
typedef float f32x4  __attribute__((ext_vector_type(4)));
typedef unsigned short u16x8 __attribute__((ext_vector_type(8)));

__device__ __forceinline__ unsigned short f2bf_rn(float f) {
    unsigned u = __float_as_uint(f);
    unsigned r = (u + 0x7FFFu + ((u >> 16) & 1u)) >> 16;
    return (unsigned short)r;
}
__device__ __forceinline__ float bf2f(unsigned short h) {
    return __uint_as_float(((unsigned)h) << 16);
}
__device__ __forceinline__ bf16x8 pack_bf8(float4 a, float4 b) {
    bf16x8 r;
    r[0] = (short)f2bf_rn(a.x); r[1] = (short)f2bf_rn(a.y);
    r[2] = (short)f2bf_rn(a.z); r[3] = (short)f2bf_rn(a.w);
    r[4] = (short)f2bf_rn(b.x); r[5] = (short)f2bf_rn(b.y);
    r[6] = (short)f2bf_rn(b.z); r[7] = (short)f2bf_rn(b.w);
    return r;
}

__device__ __forceinline__ void gload16(const void* g, void* l) {
    __builtin_amdgcn_global_load_lds(
        (const __attribute__((address_space(1))) unsigned int*)g,
        (__attribute__((address_space(3))) unsigned int*)l, 16, 0, 0);
}

// ---------------- csq[k] = sum_d C[k][d]^2 (fp32) ----------------
__global__ void csq_kernel(const float* __restrict__ C, float* __restrict__ csq) {
    int wid  = (blockIdx.x * blockDim.x + threadIdx.x) >> 6;   // one wave per k
    int lane = threadIdx.x & 63;
    const float4* p = (const float4*)(C + (size_t)wid * DIM);
    float4 a = p[lane * 2];
    float4 b = p[lane * 2 + 1];
    float s = a.x*a.x + a.y*a.y + a.z*a.z + a.w*a.w
            + b.x*b.x + b.y*b.y + b.z*b.z + b.w*b.w;
    #pragma unroll
    for (int m = 1; m < 64; m <<= 1) s += __shfl_xor(s, m, 64);
    if (lane == 0) csq[wid] = s;
}

// ---------------- fp32 -> bf16 (hi only, RN), 16B stores ----------------
__global__ void split_hi8(const float* __restrict__ src,
                          unsigned short* __restrict__ h, int n8) {
    int stride = gridDim.x * 256;
    for (int i = blockIdx.x * 256 + threadIdx.x; i < n8; i += stride) {
        const float4* p = (const float4*)(src + (size_t)i * 8);
        float4 a = p[0], b = p[1];
        u16x8 o;
        o[0] = f2bf_rn(a.x); o[1] = f2bf_rn(a.y);
        o[2] = f2bf_rn(a.z); o[3] = f2bf_rn(a.w);
        o[4] = f2bf_rn(b.x); o[5] = f2bf_rn(b.y);
        o[6] = f2bf_rn(b.z); o[7] = f2bf_rn(b.w);
        *(u16x8*)(h + (size_t)i * 8) = o;
    }
}

// ---------------- Phase 1: fused-cvt 1-pass bf16 GEMM -> fp16 scores -------
// LDS per buffer: A[0,8192) B[8192,16384); [row][group 0..3][8 elems];
// LDS[row][g] holds GLOBAL k-group g^((row>>1)&3).
// A: fp32 X loaded to regs (coalesced: 4 lanes/row contiguous), cvt RN,
//    ds_write_b128 to swizzled dest at body END (1 tile ahead).
// B: pre-split Ch via global_load_lds, source-side swizzle, linear dest.
// vmcnt discipline: top vmcnt(4) forces B(t); tail vmcnt(6) forces X(t+1).
__global__ __launch_bounds__(512, 2)
void gemm_scores(const float* __restrict__ X,
                 const unsigned short* __restrict__ Ch,
                 const float* __restrict__ csq,
                 _Float16* __restrict__ scores) {
    extern __shared__ unsigned short smem[];   // 2 * LDSBUF_F elems (64 KB)

    // XCD-aware mapping: 4 col-tiles of one row-tile run on one XCD
    // -> X fp32 tile (512 KB) L2-resident across them; Ch (1MB) L2-resident.
    int b  = blockIdx.x;
    int x  = b & 7;
    int m8 = b >> 3;                   // 0..127
    int rowtile = x * 32 + (m8 >> 2);  // 0..255
    int coltile = m8 & 3;              // 0..3
    int n0 = rowtile * 256;
    int k0 = coltile * 256;

    int tid  = threadIdx.x;
    int w    = tid >> 6;
    int lane = tid & 63;
    int wr   = w >> 2, wc = w & 3;     // 2M x 4N waves; wave tile 128x64
    int rbase = wr * 128, cbase = wc * 64;
    int lrow = lane & 15;
    int lk   = lane >> 4;
    int sg   = lk ^ ((lrow >> 1) & 3);

    // A staging: thread -> (row0 = tid>>2, g = tid&3) and (row0+128, g).
    // Lanes 0-3 cover row0's 128B contiguously (coalesced).
    int arow = tid >> 2;               // 0..127
    int ag   = tid & 3;
    int aswz = (arow >> 1) & 3;        // same for arow and arow+128
    const float* xsrc0 = X + (size_t)(n0 + arow) * DIM + ag * 8;
    const float* xsrc1 = xsrc0 + (size_t)128 * DIM;
    int adst0 = arow * 32 + (ag ^ aswz) * 8;
    int adst1 = adst0 + 4096;          // +128 rows

    // B staging via gload_lds (r11-verified)
    int srow = tid >> 2;
    int sgrp = tid & 3;
    int gB   = sgrp ^ ((srow >> 1) & 3);
    size_t oB0 = (size_t)(k0 + srow) * DIM + gB * 8;
    size_t oB1 = oB0 + (size_t)128 * DIM;
    int dB0  = 8192 + w * 512;
    int dB1  = dB0 + 4096;

    f32x4 acc[8][4];
    #pragma unroll
    for (int i = 0; i < 8; i++)
        #pragma unroll
        for (int j = 0; j < 4; j++)
            acc[i][j] = (f32x4){0.f, 0.f, 0.f, 0.f};

    auto issue_B = [&](int tn) {
        unsigned short* bufn = smem + (tn & 1) * LDSBUF_F;
        size_t d = (size_t)tn * 32;
        gload16(Ch + oB0 + d, bufn + dB0);
        gload16(Ch + oB1 + d, bufn + dB1);
    };

    // two X register sets (static names, rule #20)
    float4 ga0, ga1, gb0, gb1, fa0, fa1, fb0, fb1;

    // prologue: G <- X(0); issue B(0); F <- X(1); write A(0).
    {
        const float4* p0 = (const float4*)xsrc0;
        const float4* p1 = (const float4*)xsrc1;
        ga0 = p0[0]; ga1 = p0[1]; gb0 = p1[0]; gb1 = p1[1];
        issue_B(0);
        const float4* q0 = (const float4*)(xsrc0 + 32);
        const float4* q1 = (const float4*)(xsrc1 + 32);
        fa0 = q0[0]; fa1 = q0[1]; fb0 = q1[0]; fb1 = q1[1];
        asm volatile("s_waitcnt vmcnt(6)" ::: "memory");   // X(0) landed
        unsigned short* b0 = smem;
        *(bf16x8*)(b0 + adst0) = pack_bf8(ga0, ga1);
        *(bf16x8*)(b0 + adst1) = pack_bf8(gb0, gb1);
    }

    // body(t): FREE = regs that held X(t) (already written), reloaded with
    // X(t+2); HOLD = regs holding X(t+1), cvt+written at body end.
    auto body = [&](int t,
                    float4& ua0, float4& ua1, float4& ub0, float4& ub1,   // FREE
                    float4& va0, float4& va1, float4& vb0, float4& vb1) { // HOLD
        // top: force B(t) (and everything older); X(t+1) stays in flight
        if (t + 1 < NT) asm volatile("s_waitcnt vmcnt(4)" ::: "memory");
        else            asm volatile("s_waitcnt vmcnt(0)" ::: "memory");
        asm volatile("s_waitcnt lgkmcnt(0)" ::: "memory");  // our A-writes done
        __builtin_amdgcn_s_barrier();
        asm volatile("" ::: "memory");

        const unsigned short* buf = smem + (t & 1) * LDSBUF_F;
        const unsigned short* pA = buf + (rbase + lrow) * 32 + sg * 8;
        const unsigned short* pB = buf + 8192 + (cbase + lrow) * 32 + sg * 8;

        bf16x8 bh[4], ah[8];
        #pragma unroll
        for (int n = 0; n < 4; n++) bh[n] = *(const bf16x8*)(pB + n * 512);
        #pragma unroll
        for (int m = 0; m < 8; m++) ah[m] = *(const bf16x8*)(pA + m * 512);

        if (t + 1 < NT) issue_B(t + 1);
        if (t + 2 < NT) {
            const float4* q0 = (const float4*)(xsrc0 + (t + 2) * 32);
            const float4* q1 = (const float4*)(xsrc1 + (t + 2) * 32);
            ua0 = q0[0]; ua1 = q0[1]; ub0 = q1[0]; ub1 = q1[1];
        }

        __builtin_amdgcn_s_setprio(1);
        #pragma unroll
        for (int m = 0; m < 8; m++)
            #pragma unroll
            for (int n = 0; n < 4; n++)
                acc[m][n] = __builtin_amdgcn_mfma_f32_16x16x32_bf16(ah[m], bh[n], acc[m][n], 0, 0, 0);
        __builtin_amdgcn_s_setprio(0);

        // tail: force X(t+1); keep B(t+1) + X(t+2) in flight; write A(t+1).
        if (t + 1 < NT) {
            if (t + 2 < NT) asm volatile("s_waitcnt vmcnt(6)" ::: "memory");
            else            asm volatile("s_waitcnt vmcnt(2)" ::: "memory");
            unsigned short* nb = smem + ((t + 1) & 1) * LDSBUF_F;
            *(bf16x8*)(nb + adst0) = pack_bf8(va0, va1);
            *(bf16x8*)(nb + adst1) = pack_bf8(vb0, vb1);
        }
    };

    for (int tt = 0; tt < NT; tt += 2) {
        body(tt,     ga0, ga1, gb0, gb1, fa0, fa1, fb0, fb1);
        body(tt + 1, fa0, fa1, fb0, fb1, ga0, ga1, gb0, gb1);
    }

    // epilogue: store fp16 SCORES (csq - 2*cross).
    // C/D: col = lane&15, row = (lane>>4)*4 + reg.
    float cs[4];
    #pragma unroll
    for (int n = 0; n < 4; n++) cs[n] = csq[k0 + cbase + n * 16 + lrow];

    #pragma unroll
    for (int m = 0; m < 8; m++) {
        int grow = n0 + rbase + m * 16 + lk * 4;
        #pragma unroll
        for (int r = 0; r < 4; r++) {
            _Float16* sp = scores + (size_t)(grow + r) * K_CB + k0 + cbase + lrow;
            #pragma unroll
            for (int n = 0; n < 4; n++)
                sp[n * 16] = (_Float16)(cs[n] - 2.0f * acc[m][n][r]);
        }
    }
}

// ---------------- Phase 2: shortlist + exact certify (verified) ----------
// stored score_k ~ csq[k] - 2*x.c_k with |err| <= 2*2^-8*||x||*||c||
// + fp16 ulp <= 5.5 =: D. THR=16 > 2*D: exact argmin always in
// {k: s_k <= min_s + THR}; singleton shortlist is provably optimal.
struct H8 { _Float16 v[8]; };

__global__ __launch_bounds__(256)
void phase2_kernel(const float* __restrict__ X, const float* __restrict__ C,
                   const float* __restrict__ csq,
                   const _Float16* __restrict__ scores,
                   const int* __restrict__ classes, int* __restrict__ out) {
    int lane = threadIdx.x & 63;
    int n = blockIdx.x * 4 + (threadIdx.x >> 6);   // one wave per row

    float s[16];
    {
        const _Float16* sp16 = scores + (size_t)n * K_CB + lane * 16;
        H8 h0 = *(const H8*)sp16;
        H8 h1 = *(const H8*)(sp16 + 8);
        #pragma unroll
        for (int j = 0; j < 8; j++) {
            s[j]     = (float)h0.v[j];
            s[8 + j] = (float)h1.v[j];
        }
    }

    float mn = s[0];
    #pragma unroll
    for (int j = 1; j < 16; j++) mn = fminf(mn, s[j]);
    #pragma unroll
    for (int m = 1; m < 64; m <<= 1) mn = fminf(mn, __shfl_xor(mn, m, 64));

    float thr = mn + 16.0f;
    unsigned fl = 0;
    #pragma unroll
    for (int j = 0; j < 16; j++) fl |= (unsigned)(s[j] <= thr) << j;
    int cnt = __popc(fl);
    #pragma unroll
    for (int m = 1; m < 64; m <<= 1) cnt += __shfl_xor(cnt, m, 64);

    int bestk;
    if (cnt == 1) {
        int kk = 0x7fffffff;
        #pragma unroll
        for (int j = 0; j < 16; j++)
            if ((fl >> j) & 1) kk = lane * 16 + j;
        #pragma unroll
        for (int m = 1; m < 64; m <<= 1) kk = min(kk, __shfl_xor(kk, m, 64));
        bestk = kk;
    } else {
        const float4* xp = (const float4*)(X + (size_t)n * DIM + lane * 8);
        float4 x0 = xp[0], x1 = xp[1];
        float bv = 3.4e38f;
        int bk = 0x7fffffff;
        #pragma unroll 1
        for (int j = 0; j < 16; j++) {
            unsigned long long mask = __ballot((fl >> j) & 1);
            while (mask) {
                int l = __ffsll((unsigned long long)mask) - 1;
                mask &= mask - 1;
                int k = l * 16 + j;                       // wave-uniform
                const float4* cp = (const float4*)(C + (size_t)k * DIM + lane * 8);
                float4 y0 = cp[0], y1 = cp[1];
                float d = x0.x*y0.x + x0.y*y0.y + x0.z*y0.z + x0.w*y0.w
                        + x1.x*y1.x + x1.y*y1.y + x1.z*y1.z + x1.w*y1.w;
                #pragma unroll
                for (int m = 1; m < 64; m <<= 1) d += __shfl_xor(d, m, 64);
                float se = csq[k] - 2.0f * d;             // exact fp32 score
                if (se < bv || (se == bv && k < bk)) { bv = se; bk = k; }
            }
        }
        bestk = bk;
    }
    if (lane == 0) out[n] = classes[bestk];
}

// ======================= fallback path (round-9, verified) =================
__global__ void init_kernel(unsigned long long* __restrict__ packed) {
    int n = blockIdx.x * 256 + threadIdx.x;
    if (n < N_ROWS) packed[n] = ~0ull;
}

__global__ void split_kernel(const float* __restrict__ src,
                             unsigned short* __restrict__ h,
                             unsigned short* __restrict__ l, int n4) {
    int stride = gridDim.x * 256;
    for (int i = blockIdx.x * 256 + threadIdx.x; i < n4; i += stride) {
        float4 v = ((const float4*)src)[i];
        ushort4 hh, ll;
        float f;
        f = v.x; hh.x = f2bf_rn(f); ll.x = f2bf_rn(f - bf2f(hh.x));
        f = v.y; hh.y = f2bf_rn(f); ll.y = f2bf_rn(f - bf2f(hh.y));
        f = v.z; hh.z = f2bf_rn(f); ll.z = f2bf_rn(f - bf2f(hh.z));
        f = v.w; hh.w = f2bf_rn(f); ll.w = f2bf_rn(f - bf2f(hh.w));
        ((ushort4*)h)[i] = hh;
        ((ushort4*)l)[i] = ll;
    }
}

__global__ __launch_bounds__(512, 2)
void gemm_argmin(const unsigned short* __restrict__ Xh,
                 const unsigned short* __restrict__ Xl,
                 const unsigned short* __restrict__ Ch,
                 const unsigned short* __restrict__ Cl,
                 const float* __restrict__ csq,
                 unsigned long long* __restrict__ packed) {
    extern __shared__ unsigned short smem[];   // 2 * LDSBUF elements (128 KB)

    int b  = blockIdx.x;
    int x  = b & 7;
    int m8 = b >> 3;
    int rowtile = x * 32 + (m8 >> 2);
    int coltile = m8 & 3;
    int n0 = rowtile * 256;
    int k0 = coltile * 256;

    int tid  = threadIdx.x;
    int w    = tid >> 6;
    int lane = tid & 63;
    int wr   = w >> 2, wc = w & 3;
    int rbase = wr * 128, cbase = wc * 64;
    int lrow = lane & 15;
    int lk   = lane >> 4;
    int sg   = lk ^ ((lrow >> 1) & 3);

    int srow = tid >> 2;
    int sgrp = tid & 3;
    int r1   = (srow < 64) ? srow : srow + 64;
    int ggA  = sgrp ^ ((r1 >> 1) & 3);
    int gB   = sgrp ^ ((srow >> 1) & 3);
    size_t oA1 = (size_t)(n0 + r1) * DIM + ggA * 8;
    size_t oA2 = oA1 + (size_t)64 * DIM;
    size_t oB0 = (size_t)(k0 + srow) * DIM + gB * 8;
    size_t oB1 = oB0 + (size_t)128 * DIM;
    int rowA1_0 = (w < 4) ? w * 16 : w * 16 + 64;
    int dA1  = rowA1_0 * 32;
    int dA2  = dA1 + 2048;
    int dB0  = 16384 + w * 512;
    int dB1  = dB0 + 4096;
    int dBl0 = dB0 + 8192;
    int dBl1 = dB1 + 8192;

    f32x4 acc[8][4];
    #pragma unroll
    for (int i = 0; i < 8; i++)
        #pragma unroll
        for (int j = 0; j < 4; j++)
            acc[i][j] = (f32x4){0.f, 0.f, 0.f, 0.f};

    bf16x8 bh[4], bl[4];

    auto issue_tile = [&](int t) {
        unsigned short* bufn = smem + (t & 1) * LDSBUF;
        size_t d = (size_t)t * 32;
        gload16(Xh + oA1 + d, bufn + dA1);
        gload16(Xl + oA1 + d, bufn + 8192 + dA1);
        gload16(Ch + oB0 + d, bufn + dB0);
        gload16(Ch + oB1 + d, bufn + dB1);
        gload16(Cl + oB0 + d, bufn + dBl0);
        gload16(Cl + oB1 + d, bufn + dBl1);
        gload16(Xh + oA2 + d, bufn + dA2);
        gload16(Xl + oA2 + d, bufn + 8192 + dA2);
    };

    auto mfma_half = [&](int mb, const bf16x8* ah, const bf16x8* al) {
        __builtin_amdgcn_s_setprio(1);
        #pragma unroll
        for (int mm = 0; mm < 4; mm++)
            #pragma unroll
            for (int n = 0; n < 4; n++)
                acc[mb + mm][n] = __builtin_amdgcn_mfma_f32_16x16x32_bf16(ah[mm], bh[n], acc[mb + mm][n], 0, 0, 0);
        #pragma unroll
        for (int mm = 0; mm < 4; mm++)
            #pragma unroll
            for (int n = 0; n < 4; n++)
                acc[mb + mm][n] = __builtin_amdgcn_mfma_f32_16x16x32_bf16(ah[mm], bl[n], acc[mb + mm][n], 0, 0, 0);
        #pragma unroll
        for (int mm = 0; mm < 4; mm++)
            #pragma unroll
            for (int n = 0; n < 4; n++)
                acc[mb + mm][n] = __builtin_amdgcn_mfma_f32_16x16x32_bf16(al[mm], bh[n], acc[mb + mm][n], 0, 0, 0);
        __builtin_amdgcn_s_setprio(0);
    };

    issue_tile(0);

    for (int t = 0; t < NT; ++t) {
        asm volatile("s_waitcnt vmcnt(0)" ::: "memory");
        __builtin_amdgcn_s_barrier();
        asm volatile("" ::: "memory");

        const unsigned short* buf = smem + (t & 1) * LDSBUF;
        const unsigned short* pA = buf + (rbase + lrow) * 32 + sg * 8;
        const unsigned short* pB = buf + 16384 + (cbase + lrow) * 32 + sg * 8;

        #pragma unroll
        for (int n = 0; n < 4; n++) {
            bh[n] = *(const bf16x8*)(pB + n * 512);
            bl[n] = *(const bf16x8*)(pB + 8192 + n * 512);
        }
        bf16x8 ah[4], al[4];
        #pragma unroll
        for (int mm = 0; mm < 4; mm++) {
            ah[mm] = *(const bf16x8*)(pA + mm * 512);
            al[mm] = *(const bf16x8*)(pA + 8192 + mm * 512);
        }
        if (t + 1 < NT) issue_tile(t + 1);

        mfma_half(0, ah, al);

        bf16x8 ah2[4], al2[4];
        #pragma unroll
        for (int mm = 0; mm < 4; mm++) {
            ah2[mm] = *(const bf16x8*)(pA + (4 + mm) * 512);
            al2[mm] = *(const bf16x8*)(pA + 8192 + (4 + mm) * 512);
        }
        mfma_half(4, ah2, al2);
    }

    float cs[4];
    #pragma unroll
    for (int n = 0; n < 4; n++) cs[n] = csq[k0 + cbase + n * 16 + lrow];

    #pragma unroll
    for (int m = 0; m < 8; m++) {
        #pragma unroll
        for (int r = 0; r < 4; r++) {
            unsigned long long best = ~0ull;
            #pragma unroll
            for (int n = 0; n < 4; n++) {
                float s = cs[n] - 2.0f * acc[m][n][r];
                unsigned kb  = __float_as_uint(s);
                unsigned key = kb ^ (unsigned)(((int)kb >> 31) | 0x80000000);
                unsigned col = (unsigned)(k0 + cbase + n * 16 + lrow);
                unsigned long long pk = (((unsigned long long)key) << 32) | col;
                best = pk < best ? pk : best;
            }
            #pragma unroll
            for (int mask = 1; mask <= 8; mask <<= 1) {
                unsigned hi = __shfl_xor((unsigned)(best >> 32), mask, 64);
                unsigned lo = __shfl_xor((unsigned)(best & 0xFFFFFFFFu), mask, 64);
                unsigned long long other = (((unsigned long long)hi) << 32) | lo;
                best = other < best ? other : best;
            }
            if (lrow == 0) {
                int grow = n0 + rbase + m * 16 + lk * 4 + r;
                atomicMin(&packed[grow], best);
            }
        }
    }
}

__global__ void map_kernel(const unsigned long long* __restrict__ packed,
                           const int* __restrict__ classes,
                           int* __restrict__ out) {
    int n = blockIdx.x * 256 + threadIdx.x;
    if (n < N_ROWS) {
        unsigned col = (unsigned)(packed[n] & 0xFFFFFFFFull);
        out[n] = classes[col];
    }
}

extern "C" void kernel_launch(void* const* d_in, const int* in_sizes, int n_in,
                              void* d_out, int out_size, void* d_ws, size_t ws_size,
                              hipStream_t stream) {
    const float* X       = (const float*)d_in[0];
    const float* C       = (const float*)d_in[1];
    const int*   classes = (const int*)d_in[2];
    int*         out     = (int*)d_out;
    char* ws = (char*)d_ws;

    // ---- fast path layout: csq | Ch | scores(fp16) ----
    {
        size_t off = 0;
        float* csq = (float*)(ws + off);                  off += 4096;
        unsigned short* Ch = (unsigned short*)(ws + off); off += (size_t)K_CB * DIM * 2;
        _Float16* scores = (_Float16*)(ws + off);         off += (size_t)N_ROWS * K_CB * 2;
        if (ws_size >= off) {
            csq_kernel<<<K_CB / 4, 256, 0, stream>>>(C, csq);
            split_hi8<<<256, 256, 0, stream>>>(C, Ch, K_CB * DIM / 8);
            hipFuncSetAttribute((const void*)gemm_scores,
                                hipFuncAttributeMaxDynamicSharedMemorySize,
                                2 * LDSBUF_F * (int)sizeof(unsigned short));
            gemm_scores<<<(N_ROWS / 256) * (K_CB / 256), 512,
                          2 * LDSBUF_F * sizeof(unsigned short), stream>>>(
                X, Ch, csq, scores);
            phase2_kernel<<<N_ROWS / 4, 256, 0, stream>>>(X, C, csq, scores, classes, out);
            return;
        }
    }

    // ---- fallback: round-9 3-pass path ----
    size_t off = 0;
    unsigned long long* packed = (unsigned long long*)(ws + off); off += (size_t)N_ROWS * 8;
    float* csq = (float*)(ws + off);                              off += (size_t)K_CB * 4;
    unsigned short* Xh = (unsigned short*)(ws + off);             off += (size_t)N_ROWS * DIM * 2;
    unsigned short* Xl = (unsigned short*)(ws + off);             off += (size_t)N_ROWS * DIM * 2;
    unsigned short* Ch = (unsigned short*)(ws + off);             off += (size_t)K_CB * DIM * 2;
    unsigned short* Cl = (unsigned short*)(ws + off);             off += (size_t)K_CB * DIM * 2;

    init_kernel<<<N_ROWS / 256, 256, 0, stream>>>(packed);
    csq_kernel<<<K_CB / 4, 256, 0, stream>>>(C, csq);
    split_kernel<<<2048, 256, 0, stream>>>(X, Xh, Xl, N_ROWS * DIM / 4);
    split_kernel<<<512, 256, 0, stream>>>(C, Ch, Cl, K_CB * DIM / 4);
    hipFuncSetAttribute((const void*)gemm_argmin,
                        hipFuncAttributeMaxDynamicSharedMemorySize,
                        2 * LDSBUF * (int)sizeof(unsigned short));
    gemm_argmin<<<(N_ROWS / 256) * (K_CB / 256), 512,
                  2 * LDSBUF * sizeof(unsigned short), stream>>>(
        Xh, Xl, Ch, Cl, csq, packed);
    map_kernel<<<N_ROWS / 256, 256, 0, stream>>>(packed, classes, out);
}